// Round 8
// baseline (57.281 us; speedup 1.0000x reference)
//
#include <hip/hip_runtime.h>
#include <hip/hip_fp16.h>

#define W 256
#define NA 180
#define SPLIT 4
#define GANG 3            // angles per block
#define NGROUPS 60        // 60 * GANG = 180 angles
#define ROWBYTES 580      // 290 halfs = 145 words; odd word stride
#define ROWS 259          // data rows 1..256 (pixel y + 1); cols 2..257 (pixel x + 2)

__global__ __launch_bounds__(1024) void radon_kernel(
    const float* __restrict__ x, const int* __restrict__ index_p,
    float* __restrict__ out)
{
    __shared__ __half simg[ROWS * 290];   // 150,220 B — image, persists across angles
    __shared__ float red[2 * SPLIT * W];  // 8,192 B — per-angle reduction scratch

    const int grp = blockIdx.x;      // angle group 0..59
    const int n = blockIdx.y;        // batch
    const int tid = threadIdx.x;
    const int c = tid & (W - 1);     // column 0..255
    const int s = tid >> 8;          // r-chunk 0..3 (wave-uniform)

    const float* __restrict__ img = x + (size_t)n * W * W;

    // ---- guard zero-fill (cells disjoint from staged data) ----
    {
        unsigned* wp = (unsigned*)simg;
        if (tid < 435) {                       // rows 0,257,258: 3 x 145 words
            const int rr = tid / 145;
            const int w = tid - rr * 145;
            const int row = (rr == 0) ? 0 : (256 + rr);
            wp[row * 145 + w] = 0u;
        } else if (tid < 947) {                // col guards, rows 1..256
            const int i = tid - 435;
            const int row = 1 + (i >> 1);
            const int w = (i & 1) ? 129 : 0;   // halfs {258,259} : {0,1}
            wp[row * 145 + w] = 0u;
        }
    }

    // ---- stage image -> LDS fp16 ----
    {
        const float4* img4 = (const float4*)img;
        #pragma unroll
        for (int k = 0; k < 16; ++k) {
            const int g = k * 1024 + tid;
            const int row = (g >> 6) + 1;      // 1..256
            const int m = g & 63;
            const float4 v = img4[g];
            const __half2 h01 = __floats2half2_rn(v.x, v.y);
            const __half2 h23 = __floats2half2_rn(v.z, v.w);
            char* base = (char*)simg + row * ROWBYTES + 8 * m + 4;  // col 4m+2
            *(unsigned*)(base)     = *(const unsigned*)&h01;
            *(unsigned*)(base + 4) = *(const unsigned*)&h23;
        }
    }
    __syncthreads();

    const int index = *index_p;
    const int seg[6] = {1, 26, 51, 77, 102, 128};
    const int t0 = seg[4 - index];
    const int t1 = seg[4 - index + 1];

    const float xc = ((2.0f * (float)c + 1.0f) * (1.0f / (float)W)) - 1.0f;

    const int r1lo = 128 - t1;
    const int r0lo = 128 - t0, r0hi = 127 + t0;
    const int total = 2 * t1;
    const int chunk = (total + SPLIT - 1) / SPLIT;
    const int rs = r1lo + s * chunk;
    const int re = min(rs + chunk, r1lo + total);

    const char* S = (const char*)simg;
    const float inv0 = 1.0f / (float)(2 * t0);
    const float inv1 = 1.0f / (float)(2 * t1);

    for (int j = 0; j < GANG; ++j) {
        const int a = grp * GANG + j;

        float sa, ca;
        sincosf((float)a * 0.017453292519943295f, &sa, &ca);
        // biased bases: +2 in x, +1 in y (floor(v)+k == floor(v+k))
        const float bx = fmaf(128.0f * ca, xc, 127.5f + 2.0f);
        const float by = fmaf(-128.0f * sa, xc, 127.5f + 1.0f);

        float sum0 = 0.0f, sum1 = 0.0f;
        float rf = (float)rs - 127.5f;
        #pragma unroll 4
        for (int r = rs; r < re; ++r, rf += 1.0f) {
            float ix = fmaf(sa, rf, bx);
            float iy = fmaf(ca, rf, by);
            ix = fminf(fmaxf(ix, 1.0f), 258.0f);   // clamp == per-tap zeroing via guards
            iy = fminf(fmaxf(iy, 0.0f), 257.0f);
            const float ix0f = floorf(ix);
            const float iy0f = floorf(iy);
            const float wx = ix - ix0f;
            const float wy = iy - iy0f;
            const int x0 = (int)ix0f;
            const int y0 = (int)iy0f;

            // four mutually-opaque addresses: prevent u16->unaligned-b32 merging
            const int base = y0 * ROWBYTES + x0 * 2;
            int a00 = base;
            int a01 = base + 2;
            int a10 = base + ROWBYTES;
            int a11 = base + ROWBYTES + 2;
            asm volatile("" : "+v"(a00), "+v"(a01), "+v"(a10), "+v"(a11));

            const float v00 = __half2float(*(const __half*)(S + a00));
            const float v01 = __half2float(*(const __half*)(S + a01));
            const float v10 = __half2float(*(const __half*)(S + a10));
            const float v11 = __half2float(*(const __half*)(S + a11));

            const float top = fmaf(wx, v01 - v00, v00);
            const float bot = fmaf(wx, v11 - v10, v10);
            const float val = fmaf(wy, bot - top, top);

            sum1 += val;
            if (r >= r0lo && r <= r0hi) sum0 += val;
        }

        // ---- per-angle reduction (scratch does NOT alias the image) ----
        __syncthreads();                       // previous phase's scratch reads done
        red[(0 * SPLIT + s) * W + c] = sum0;
        red[(1 * SPLIT + s) * W + c] = sum1;
        __syncthreads();

        if (s == 0) {
            const float acc0 = red[0 * W + c] + red[1 * W + c] + red[2 * W + c] + red[3 * W + c];
            const float* r1p = red + SPLIT * W;
            const float acc1 = r1p[0 * W + c] + r1p[1 * W + c] + r1p[2 * W + c] + r1p[3 * W + c];
            out[(((size_t)n * 2 + 0) * W + c) * NA + a] = acc0 * inv0;
            out[(((size_t)n * 2 + 1) * W + c) * NA + a] = acc1 * inv1;
        }
    }
}

extern "C" void kernel_launch(void* const* d_in, const int* in_sizes, int n_in,
                              void* d_out, int out_size, void* d_ws, size_t ws_size,
                              hipStream_t stream) {
    const float* x = (const float*)d_in[0];
    const int* index_p = (const int*)d_in[1];
    float* out = (float*)d_out;
    const int N = in_sizes[0] / (W * W); // 4
    dim3 grid(NGROUPS, N);
    radon_kernel<<<grid, 1024, 0, stream>>>(x, index_p, out);
}

// Round 9
// 48.892 us; speedup vs baseline: 1.1716x; 1.1716x over previous
//
#include <hip/hip_runtime.h>
#include <hip/hip_fp16.h>

#define W 256
#define NA 180
#define SPLIT 4
#define ROWBYTES 580          // 290 halfs = 145 words; odd word stride -> axis walks spread over all 32 banks
#define ROWS 259              // data rows 1..256 (pixel y + 1); cols 2..257 (pixel x + 2)

__global__ __launch_bounds__(1024) void radon_kernel(
    const float* __restrict__ x, const int* __restrict__ index_p,
    float* __restrict__ out)
{
    __shared__ __half simg[ROWS * 290];   // 150,220 B

    const int a = blockIdx.x;        // angle 0..179
    const int n = blockIdx.y;        // batch
    const int tid = threadIdx.x;
    const int c = tid & (W - 1);     // column 0..255
    const int s = tid >> 8;          // r-chunk 0..3 (wave-uniform)

    const float* __restrict__ img = x + (size_t)n * W * W;

    // ---- guard zero-fill (cells disjoint from staged data -> one barrier total) ----
    {
        unsigned* wp = (unsigned*)simg;
        if (tid < 435) {                       // rows 0,257,258: 3 x 145 words
            const int rr = tid / 145;
            const int w = tid - rr * 145;
            const int row = (rr == 0) ? 0 : (256 + rr);   // 0,257,258
            wp[row * 145 + w] = 0u;
        } else if (tid < 947) {                // col guards, rows 1..256
            const int i = tid - 435;           // 0..511
            const int row = 1 + (i >> 1);
            const int w = (i & 1) ? 129 : 0;   // halfs {258,259} : {0,1}
            wp[row * 145 + w] = 0u;
        }
    }

    // ---- stage image -> LDS fp16 ----
    {
        const float4* img4 = (const float4*)img;
        #pragma unroll
        for (int k = 0; k < 16; ++k) {
            const int g = k * 1024 + tid;      // float4 group
            const int row = (g >> 6) + 1;      // 1..256
            const int m = g & 63;
            const float4 v = img4[g];
            const __half2 h01 = __floats2half2_rn(v.x, v.y);
            const __half2 h23 = __floats2half2_rn(v.z, v.w);
            char* base = (char*)simg + row * ROWBYTES + 8 * m + 4;  // col 4m+2
            *(unsigned*)(base)     = *(const unsigned*)&h01;
            *(unsigned*)(base + 4) = *(const unsigned*)&h23;
        }
    }
    __syncthreads();

    const int index = *index_p;
    const int seg[6] = {1, 26, 51, 77, 102, 128};
    const int t0 = seg[4 - index];
    const int t1 = seg[4 - index + 1];

    float sa, ca;
    sincosf((float)a * 0.017453292519943295f, &sa, &ca);

    const float xc = ((2.0f * (float)c + 1.0f) * (1.0f / (float)W)) - 1.0f;
    // biased bases: +2 in x, +1 in y (floor(v)+k == floor(v+k))
    const float bx = fmaf(128.0f * ca, xc, 127.5f + 2.0f);
    const float by = fmaf(-128.0f * sa, xc, 127.5f + 1.0f);

    const int r1lo = 128 - t1;
    const int r0lo = 128 - t0, r0hi = 127 + t0;
    const int total = 2 * t1;
    const int chunk = (total + SPLIT - 1) / SPLIT;
    const int rs = r1lo + s * chunk;
    const int re = min(rs + chunk, r1lo + total);

    float sum0 = 0.0f, sum1 = 0.0f;
    const char* S = (const char*)simg;

    float rf = (float)rs - 127.5f;
    #pragma unroll 4
    for (int r = rs; r < re; ++r, rf += 1.0f) {
        float ix = fmaf(sa, rf, bx);
        float iy = fmaf(ca, rf, by);
        ix = __builtin_amdgcn_fmed3f(ix, 1.0f, 258.0f);   // clamp -> guard cells give per-tap zeroing
        iy = __builtin_amdgcn_fmed3f(iy, 0.0f, 257.0f);
        const float ix0f = floorf(ix);
        const float iy0f = floorf(iy);
        const float wx = ix - ix0f;
        const float wy = iy - iy0f;
        const int x0 = (int)ix0f;
        const int y0 = (int)iy0f;

        // Two aligned dwords per row cover halfs {x0, x0+1} for either parity.
        // Loads at (+0,+580) and (+4,+584) -> two ds_read2_b32 (offsets {k,k+145}).
        const int sh = (x0 & 1) << 4;
        const char* p = S + (y0 * ROWBYTES + (x0 >> 1) * 4);
        const unsigned A0 = *(const unsigned*)(p);
        const unsigned A1 = *(const unsigned*)(p + ROWBYTES);
        const unsigned B0 = *(const unsigned*)(p + 4);
        const unsigned B1 = *(const unsigned*)(p + ROWBYTES + 4);

        // ({B,A} >> sh) low dword = packed halfs (x0, x0+1)  -> v_alignbit_b32
        const unsigned q0 = (unsigned)(((((unsigned long long)B0) << 32) | A0) >> sh);
        const unsigned q1 = (unsigned)(((((unsigned long long)B1) << 32) | A1) >> sh);
        const __half2 h0 = *(const __half2*)&q0;
        const __half2 h1 = *(const __half2*)&q1;
        const float v00 = __low2float(h0);
        const float v01 = __high2float(h0);
        const float v10 = __low2float(h1);
        const float v11 = __high2float(h1);

        const float top = fmaf(wx, v01 - v00, v00);
        const float bot = fmaf(wx, v11 - v10, v10);
        const float val = fmaf(wy, bot - top, top);

        sum1 += val;
        if (r >= r0lo && r <= r0hi) sum0 += val;
    }

    // ---- reduce partials; reuse simg as scratch ----
    __syncthreads();
    float* red = (float*)simg;                 // 8 KB of 150 KB
    red[(0 * SPLIT + s) * W + c] = sum0;
    red[(1 * SPLIT + s) * W + c] = sum1;
    __syncthreads();

    if (s == 0) {
        const float acc0 = red[0 * W + c] + red[1 * W + c] + red[2 * W + c] + red[3 * W + c];
        const float* r1p = red + SPLIT * W;
        const float acc1 = r1p[0 * W + c] + r1p[1 * W + c] + r1p[2 * W + c] + r1p[3 * W + c];
        out[(((size_t)n * 2 + 0) * W + c) * NA + a] = acc0 * (1.0f / (float)(2 * t0));
        out[(((size_t)n * 2 + 1) * W + c) * NA + a] = acc1 * (1.0f / (float)(2 * t1));
    }
}

extern "C" void kernel_launch(void* const* d_in, const int* in_sizes, int n_in,
                              void* d_out, int out_size, void* d_ws, size_t ws_size,
                              hipStream_t stream) {
    const float* x = (const float*)d_in[0];
    const int* index_p = (const int*)d_in[1];
    float* out = (float*)d_out;
    const int N = in_sizes[0] / (W * W); // 4
    dim3 grid(NA, N);
    radon_kernel<<<grid, 1024, 0, stream>>>(x, index_p, out);
}

// Round 10
// 46.906 us; speedup vs baseline: 1.2212x; 1.0423x over previous
//
#include <hip/hip_runtime.h>
#include <hip/hip_fp16.h>

#define W 256
#define NA 180
#define SPLIT 4
#define ROWBYTES 580          // 290 halfs = 145 words; odd word stride -> axis walks spread over all 32 banks
#define ROWS 259              // data rows 1..256 (pixel y + 1); cols 2..257 (pixel x + 2)

__global__ __launch_bounds__(1024) void radon_kernel(
    const float* __restrict__ x, const int* __restrict__ index_p,
    float* __restrict__ out)
{
    __shared__ __half simg[ROWS * 290];   // 150,220 B

    const int a = blockIdx.x;        // angle 0..179
    const int n = blockIdx.y;        // batch
    const int tid = threadIdx.x;
    const int c = tid & (W - 1);     // column 0..255
    const int s = tid >> 8;          // r-chunk 0..3 (wave-uniform)

    const float* __restrict__ img = x + (size_t)n * W * W;

    // ---- guard zero-fill (cells disjoint from staged data -> one barrier total) ----
    {
        unsigned* wp = (unsigned*)simg;
        if (tid < 435) {                       // rows 0,257,258: 3 x 145 words
            const int rr = tid / 145;
            const int w = tid - rr * 145;
            const int row = (rr == 0) ? 0 : (256 + rr);   // 0,257,258
            wp[row * 145 + w] = 0u;
        } else if (tid < 947) {                // col guards, rows 1..256
            const int i = tid - 435;           // 0..511
            const int row = 1 + (i >> 1);
            const int w = (i & 1) ? 129 : 0;   // halfs {258,259} : {0,1}
            wp[row * 145 + w] = 0u;
        }
    }

    // ---- stage image -> LDS fp16 ----
    {
        const float4* img4 = (const float4*)img;
        #pragma unroll
        for (int k = 0; k < 16; ++k) {
            const int g = k * 1024 + tid;      // float4 group
            const int row = (g >> 6) + 1;      // 1..256
            const int m = g & 63;
            const float4 v = img4[g];
            const __half2 h01 = __floats2half2_rn(v.x, v.y);
            const __half2 h23 = __floats2half2_rn(v.z, v.w);
            char* base = (char*)simg + row * ROWBYTES + 8 * m + 4;  // col 4m+2
            *(unsigned*)(base)     = *(const unsigned*)&h01;
            *(unsigned*)(base + 4) = *(const unsigned*)&h23;
        }
    }
    __syncthreads();

    const int index = *index_p;
    const int seg[6] = {1, 26, 51, 77, 102, 128};
    const int t0 = seg[4 - index];
    const int t1 = seg[4 - index + 1];

    float sa, ca;
    sincosf((float)a * 0.017453292519943295f, &sa, &ca);

    const float xc = ((2.0f * (float)c + 1.0f) * (1.0f / (float)W)) - 1.0f;
    // biased bases: +2 in x, +1 in y (floor(v)+k == floor(v+k))
    const float bx = fmaf(128.0f * ca, xc, 127.5f + 2.0f);
    const float by = fmaf(-128.0f * sa, xc, 127.5f + 1.0f);

    const int r1lo = 128 - t1;
    const int r0lo = 128 - t0, r0hi = 127 + t0;
    const int total = 2 * t1;
    const int chunk = (total + SPLIT - 1) / SPLIT;
    const int rs = r1lo + s * chunk;
    const int re = min(rs + chunk, r1lo + total);

    const char* S = (const char*)simg;

#define TAP_BODY                                                              \
        float ix = fmaf(sa, rf, bx);                                          \
        float iy = fmaf(ca, rf, by);                                          \
        ix = __builtin_amdgcn_fmed3f(ix, 1.0f, 258.0f);                       \
        iy = __builtin_amdgcn_fmed3f(iy, 0.0f, 257.0f);                       \
        const float ix0f = floorf(ix);                                        \
        const float iy0f = floorf(iy);                                        \
        const float wx = ix - ix0f;                                           \
        const float wy = iy - iy0f;                                           \
        const int x0 = (int)ix0f;                                             \
        const int y0 = (int)iy0f;                                             \
        const int sh = (x0 & 1) << 4;                                         \
        const char* p = S + (y0 * ROWBYTES + (x0 >> 1) * 4);                  \
        const unsigned A0 = *(const unsigned*)(p);                            \
        const unsigned A1 = *(const unsigned*)(p + ROWBYTES);                 \
        const unsigned B0 = *(const unsigned*)(p + 4);                        \
        const unsigned B1 = *(const unsigned*)(p + ROWBYTES + 4);             \
        const unsigned q0 = (unsigned)(((((unsigned long long)B0) << 32) | A0) >> sh); \
        const unsigned q1 = (unsigned)(((((unsigned long long)B1) << 32) | A1) >> sh); \
        const __half2 h0 = *(const __half2*)&q0;                              \
        const __half2 h1 = *(const __half2*)&q1;                              \
        const float v00 = __low2float(h0);                                    \
        const float v01 = __high2float(h0);                                   \
        const float v10 = __low2float(h1);                                    \
        const float v11 = __high2float(h1);                                   \
        const float top = fmaf(wx, v01 - v00, v00);                           \
        const float bot = fmaf(wx, v11 - v10, v10);                           \
        const float val = fmaf(wy, bot - top, top);

    float sumA = 0.0f, sumB = 0.0f, sumC = 0.0f;

    // segment A: [rs, min(re, r0lo)) -> outer only
    {
        const int e = min(re, r0lo);
        float rf = (float)rs - 127.5f;
        #pragma unroll 8
        for (int r = rs; r < e; ++r, rf += 1.0f) { TAP_BODY sumA += val; }
    }
    // segment B: [max(rs, r0lo), min(re, r0hi+1)) -> both masks
    {
        const int b = max(rs, r0lo);
        const int e = min(re, r0hi + 1);
        float rf = (float)b - 127.5f;
        #pragma unroll 8
        for (int r = b; r < e; ++r, rf += 1.0f) { TAP_BODY sumB += val; }
    }
    // segment C: [max(rs, r0hi+1), re) -> outer only
    {
        const int b = max(rs, r0hi + 1);
        float rf = (float)b - 127.5f;
        #pragma unroll 8
        for (int r = b; r < re; ++r, rf += 1.0f) { TAP_BODY sumC += val; }
    }
#undef TAP_BODY

    const float sum0 = sumB;
    const float sum1 = sumA + sumB + sumC;

    // ---- reduce partials; reuse simg as scratch ----
    __syncthreads();
    float* red = (float*)simg;                 // 8 KB of 150 KB
    red[(0 * SPLIT + s) * W + c] = sum0;
    red[(1 * SPLIT + s) * W + c] = sum1;
    __syncthreads();

    if (s == 0) {
        const float acc0 = red[0 * W + c] + red[1 * W + c] + red[2 * W + c] + red[3 * W + c];
        const float* r1p = red + SPLIT * W;
        const float acc1 = r1p[0 * W + c] + r1p[1 * W + c] + r1p[2 * W + c] + r1p[3 * W + c];
        out[(((size_t)n * 2 + 0) * W + c) * NA + a] = acc0 * (1.0f / (float)(2 * t0));
        out[(((size_t)n * 2 + 1) * W + c) * NA + a] = acc1 * (1.0f / (float)(2 * t1));
    }
}

extern "C" void kernel_launch(void* const* d_in, const int* in_sizes, int n_in,
                              void* d_out, int out_size, void* d_ws, size_t ws_size,
                              hipStream_t stream) {
    const float* x = (const float*)d_in[0];
    const int* index_p = (const int*)d_in[1];
    float* out = (float*)d_out;
    const int N = in_sizes[0] / (W * W); // 4
    dim3 grid(NA, N);
    radon_kernel<<<grid, 1024, 0, stream>>>(x, index_p, out);
}

// Round 11
// 46.535 us; speedup vs baseline: 1.2309x; 1.0080x over previous
//
#include <hip/hip_runtime.h>
#include <hip/hip_fp16.h>

#define W 256
#define NA 180
#define SPLIT 4
#define ROWBYTES 580          // 290 halfs = 145 words; odd word stride -> axis walks spread over all 32 banks
#define ROWS 259              // data rows 1..256 (pixel y + 1); cols 2..257 (pixel x + 2)

// LDS (150 KB) caps us at 1 block/CU = 4 waves/SIMD. Tell the allocator so it
// trades (useless) occupancy headroom for ILP: 128-VGPR budget.
__global__ __launch_bounds__(1024, 4) void radon_kernel(
    const float* __restrict__ x, const int* __restrict__ index_p,
    float* __restrict__ out)
{
    __shared__ __half simg[ROWS * 290];   // 150,220 B

    const int a = blockIdx.x;        // angle 0..179
    const int n = blockIdx.y;        // batch
    const int tid = threadIdx.x;
    const int c = tid & (W - 1);     // column 0..255
    const int s = tid >> 8;          // r-chunk 0..3 (wave-uniform)

    const float* __restrict__ img = x + (size_t)n * W * W;

    // ---- guard zero-fill (cells disjoint from staged data -> one barrier total) ----
    {
        unsigned* wp = (unsigned*)simg;
        if (tid < 435) {                       // rows 0,257,258: 3 x 145 words
            const int rr = tid / 145;
            const int w = tid - rr * 145;
            const int row = (rr == 0) ? 0 : (256 + rr);   // 0,257,258
            wp[row * 145 + w] = 0u;
        } else if (tid < 947) {                // col guards, rows 1..256
            const int i = tid - 435;           // 0..511
            const int row = 1 + (i >> 1);
            const int w = (i & 1) ? 129 : 0;   // halfs {258,259} : {0,1}
            wp[row * 145 + w] = 0u;
        }
    }

    // ---- stage image -> LDS fp16 ----
    {
        const float4* img4 = (const float4*)img;
        #pragma unroll
        for (int k = 0; k < 16; ++k) {
            const int g = k * 1024 + tid;      // float4 group
            const int row = (g >> 6) + 1;      // 1..256
            const int m = g & 63;
            const float4 v = img4[g];
            const __half2 h01 = __floats2half2_rn(v.x, v.y);
            const __half2 h23 = __floats2half2_rn(v.z, v.w);
            char* base = (char*)simg + row * ROWBYTES + 8 * m + 4;  // col 4m+2
            *(unsigned*)(base)     = *(const unsigned*)&h01;
            *(unsigned*)(base + 4) = *(const unsigned*)&h23;
        }
    }
    __syncthreads();

    const int index = *index_p;
    const int seg[6] = {1, 26, 51, 77, 102, 128};
    const int t0 = seg[4 - index];
    const int t1 = seg[4 - index + 1];

    float sa, ca;
    sincosf((float)a * 0.017453292519943295f, &sa, &ca);

    const float xc = ((2.0f * (float)c + 1.0f) * (1.0f / (float)W)) - 1.0f;
    // biased bases: +2 in x, +1 in y (floor(v)+k == floor(v+k))
    const float bx = fmaf(128.0f * ca, xc, 127.5f + 2.0f);
    const float by = fmaf(-128.0f * sa, xc, 127.5f + 1.0f);

    const int r1lo = 128 - t1;
    const int r0lo = 128 - t0, r0hi = 127 + t0;
    const int total = 2 * t1;
    const int chunk = (total + SPLIT - 1) / SPLIT;
    const int rs = r1lo + s * chunk;
    const int re = min(rs + chunk, r1lo + total);

    const char* S = (const char*)simg;

#define TAP_BODY                                                              \
        float ix = fmaf(sa, rf, bx);                                          \
        float iy = fmaf(ca, rf, by);                                          \
        ix = __builtin_amdgcn_fmed3f(ix, 1.0f, 258.0f);                       \
        iy = __builtin_amdgcn_fmed3f(iy, 0.0f, 257.0f);                       \
        const float wx = __builtin_amdgcn_fractf(ix);  /* == ix - floor(ix) */\
        const float wy = __builtin_amdgcn_fractf(iy);                         \
        const int x0 = (int)ix;   /* trunc == floor: ix >= 0 */               \
        const int y0 = (int)iy;                                               \
        const int sh = (x0 & 1) << 4;                                         \
        const char* p = S + (y0 * ROWBYTES + (x0 >> 1) * 4);                  \
        const unsigned A0 = *(const unsigned*)(p);                            \
        const unsigned A1 = *(const unsigned*)(p + ROWBYTES);                 \
        const unsigned B0 = *(const unsigned*)(p + 4);                        \
        const unsigned B1 = *(const unsigned*)(p + ROWBYTES + 4);             \
        const unsigned q0 = (unsigned)(((((unsigned long long)B0) << 32) | A0) >> sh); \
        const unsigned q1 = (unsigned)(((((unsigned long long)B1) << 32) | A1) >> sh); \
        const __half2 h0 = *(const __half2*)&q0;                              \
        const __half2 h1 = *(const __half2*)&q1;                              \
        const float v00 = __low2float(h0);                                    \
        const float v01 = __high2float(h0);                                   \
        const float v10 = __low2float(h1);                                    \
        const float v11 = __high2float(h1);                                   \
        const float top = fmaf(wx, v01 - v00, v00);                           \
        const float bot = fmaf(wx, v11 - v10, v10);                           \
        const float val = fmaf(wy, bot - top, top);

    float sumA = 0.0f, sumB = 0.0f, sumC = 0.0f;

    // segment A: [rs, min(re, r0lo)) -> outer only
    {
        const int e = min(re, r0lo);
        float rf = (float)rs - 127.5f;
        #pragma unroll 8
        for (int r = rs; r < e; ++r, rf += 1.0f) { TAP_BODY sumA += val; }
    }
    // segment B: [max(rs, r0lo), min(re, r0hi+1)) -> both masks
    {
        const int b = max(rs, r0lo);
        const int e = min(re, r0hi + 1);
        float rf = (float)b - 127.5f;
        #pragma unroll 8
        for (int r = b; r < e; ++r, rf += 1.0f) { TAP_BODY sumB += val; }
    }
    // segment C: [max(rs, r0hi+1), re) -> outer only
    {
        const int b = max(rs, r0hi + 1);
        float rf = (float)b - 127.5f;
        #pragma unroll 8
        for (int r = b; r < re; ++r, rf += 1.0f) { TAP_BODY sumC += val; }
    }
#undef TAP_BODY

    const float sum0 = sumB;
    const float sum1 = sumA + sumB + sumC;

    // ---- reduce partials; reuse simg as scratch ----
    __syncthreads();
    float* red = (float*)simg;                 // 8 KB of 150 KB
    red[(0 * SPLIT + s) * W + c] = sum0;
    red[(1 * SPLIT + s) * W + c] = sum1;
    __syncthreads();

    if (s == 0) {
        const float acc0 = red[0 * W + c] + red[1 * W + c] + red[2 * W + c] + red[3 * W + c];
        const float* r1p = red + SPLIT * W;
        const float acc1 = r1p[0 * W + c] + r1p[1 * W + c] + r1p[2 * W + c] + r1p[3 * W + c];
        out[(((size_t)n * 2 + 0) * W + c) * NA + a] = acc0 * (1.0f / (float)(2 * t0));
        out[(((size_t)n * 2 + 1) * W + c) * NA + a] = acc1 * (1.0f / (float)(2 * t1));
    }
}

extern "C" void kernel_launch(void* const* d_in, const int* in_sizes, int n_in,
                              void* d_out, int out_size, void* d_ws, size_t ws_size,
                              hipStream_t stream) {
    const float* x = (const float*)d_in[0];
    const int* index_p = (const int*)d_in[1];
    float* out = (float*)d_out;
    const int N = in_sizes[0] / (W * W); // 4
    dim3 grid(NA, N);
    radon_kernel<<<grid, 1024, 0, stream>>>(x, index_p, out);
}